// Round 7
// baseline (15735.892 us; speedup 1.0000x reference)
//
#include <hip/hip_runtime.h>

#define B_    512
#define L_    16
#define IN_   128
#define H_    1024
#define T_    64
#define OUTROW 10240   /* (L_+T_)*IN_ */

#define LDC   1040     /* c state fp32 row stride (padded) */
#define LDXL  144      /* XL fp32 row stride */
#define RSTRIDE 67     /* padded fp32 row stride in LDS reduction buffer */
#define RSZ   (64 * RSTRIDE)   /* per-wave region, proj64 (64 rows) */
#define RSZ2  (32 * RSTRIDE)   /* per-wave region, cells (32-row rounds) */

/* ---- fragment-linear bf16 operand layout ----
   fragment = 16 rows x 32 k-cols = 1024B, lane-linear:
     elem(row,k) @ u16 index  frag*512 + ((k&31)>>3)*128 + (row&15)*8 + (k&7)
     frag = (row>>4)*KH + (k>>5),  KH = K/32 */
#define KH_X  64   /* Xb   : 2048 cols */
#define KH_H  32   /* H    : 1024 cols */
#define KH_XL 4    /* XLbf : 128 cols  */
#define KH_W0 36   /* W0c  : 1152      */
#define KH_W1 64   /* W1c  : 2048      */
#define KH_WO 32   /* Woutb: 1024      */

typedef __attribute__((ext_vector_type(8))) short bf8;
typedef __attribute__((ext_vector_type(4))) float f4;
typedef __attribute__((ext_vector_type(2))) float f2;
typedef __attribute__((ext_vector_type(4))) unsigned short us4;
typedef unsigned short u16;
typedef unsigned int   u32;

#define MFMA16(a, b, c) __builtin_amdgcn_mfma_f32_16x16x32_bf16(a, b, c, 0, 0, 0)

__device__ __forceinline__ u16 f2bf(float f) {
    u32 u = __builtin_bit_cast(u32, f);
    u32 r = (u + 0x7fffu + ((u >> 16) & 1u)) >> 16;
    return (u16)r;
}
__device__ __forceinline__ float sigm(float x) { return 1.f / (1.f + __expf(-x)); }
__device__ __forceinline__ float tanh_f(float x) {
    float ax = fabsf(x);
    float e = __expf(-2.f * ax);
    float t = (1.f - e) / (1.f + e);
    return x < 0.f ? -t : t;
}
__device__ __forceinline__ bf8 ld8(const u16* p) { return *(const bf8*)p; }

__device__ __forceinline__ size_t swz(int kh_stride, int row, int k) {
    return ((size_t)(row >> 4) * kh_stride + (k >> 5)) * 512
           + ((k & 31) >> 3) * 128 + (row & 15) * 8 + (k & 7);
}

// 16-MFMA pack on one 32-col fragment set
#define MFMAP(AS, BS)                                                       \
  do {                                                                      \
    _Pragma("unroll")                                                       \
    for (int g_ = 0; g_ < 4; ++g_)                                          \
      _Pragma("unroll")                                                     \
      for (int t_ = 0; t_ < 4; ++t_)                                        \
        acc[g_][t_] = MFMA16(AS[g_], BS[t_], acc[g_][t_]);                  \
  } while (0)

// Load fragment set for 32-col phase PH of this wave's sequence.
#define LOADP_CELL(AS, BS, PH)                                              \
  do {                                                                      \
    const int kt_ = ws + (((PH) >> 1) << 2);                                \
    const int s_  = (PH) & 1;                                               \
    const bool ix_ = kt_ < nk1;                                             \
    const int oA_ = (((ix_ ? kt_ : kt_ - nk1) << 1) + s_) * 512;            \
    const int oB_ = ((kt_ << 1) + s_) * 512;                                \
    _Pragma("unroll")                                                       \
    for (int g_ = 0; g_ < 4; ++g_)                                          \
      AS[g_] = ld8((ix_ ? apx[g_] : aph[g_]) + oA_);                        \
    _Pragma("unroll")                                                       \
    for (int t_ = 0; t_ < 4; ++t_) BS[t_] = ld8(bp[t_] + oB_);              \
  } while (0)

// ---- LSTM cell body: 4-wave split-K GEMM with 4-deep register pipeline +
// 2-round chunked LDS reduction (34.3 KB -> 4 blocks/CU co-residency for the
// 1024-block prompt pairs) + fused cell epilogue. Bit-identical numerics to
// the single-round form (same add order). Requires nph >= 8 (nk in {18, 32}).
__device__ __forceinline__ void cell_body(int bid,
    const u16* __restrict__ pA0, int kh0, int nk1,
    const u16* __restrict__ pA1, int kh1, int nk2,
    const u16* __restrict__ pB, int khB,
    const float* __restrict__ bias, float* __restrict__ Cst,
    u16* __restrict__ Hdst, float* __restrict__ red)
{
    const int tn = (bid & 7) * 8 + ((bid >> 3) & 7);   // XCD-pins tn slice
    const int tm = bid >> 6;
    const int tid = threadIdx.x;
    const int lane = tid & 63, ws = tid >> 6;
    const int l15 = lane & 15, qd = lane >> 4, q4 = qd * 4;

    // epilogue coords: thread -> rows {r_row, 32+r_row}, units r_u..r_u+1
    const int r_row = tid >> 3;          // 0..31
    const int r_u   = (tid & 7) << 1;    // 0,2,..,14
    const int ecol  = tn * 16 + r_u;
    // prefetch c RMW values now (hidden under whole GEMM)
    const f2 coldA = *(const f2*)&Cst[(size_t)(tm * 64 + r_row) * LDC + ecol];
    const f2 coldB = *(const f2*)&Cst[(size_t)(tm * 64 + 32 + r_row) * LDC + ecol];

    f4 acc[4][4];
#pragma unroll
    for (int i = 0; i < 4; ++i)
#pragma unroll
        for (int j = 0; j < 4; ++j) acc[i][j] = (f4)(0.f);

    const u16* bp[4];
#pragma unroll
    for (int t = 0; t < 4; ++t)
        bp[t] = pB + (size_t)(tn * 4 + t) * khB * 512 + lane * 8;
    const u16* apx[4];
    const u16* aph[4];
#pragma unroll
    for (int g = 0; g < 4; ++g) {
        apx[g] = pA0 + (size_t)(tm * 4 + g) * kh0 * 512 + lane * 8;
        aph[g] = pA1 + (size_t)(tm * 4 + g) * kh1 * 512 + lane * 8;
    }

    const int nk  = nk1 + nk2;
    const int myn = (nk - ws + 3) >> 2;
    const int nph = myn * 2;                // even, >= 8 for all shapes used

    bf8 A0[4], B0[4], A1[4], B1[4], A2[4], B2[4], A3[4], B3[4];
    LOADP_CELL(A0, B0, 0);
    LOADP_CELL(A1, B1, 1);
    LOADP_CELL(A2, B2, 2);
    int ph = 0;
    for (; ph + 4 <= nph; ph += 4) {
        LOADP_CELL(A3, B3, ph + 3);
        MFMAP(A0, B0);
        if (ph + 4 < nph) LOADP_CELL(A0, B0, ph + 4);
        MFMAP(A1, B1);
        if (ph + 5 < nph) LOADP_CELL(A1, B1, ph + 5);
        MFMAP(A2, B2);
        if (ph + 6 < nph) LOADP_CELL(A2, B2, ph + 6);
        MFMAP(A3, B3);
    }
    if (ph < nph) {                          // nph % 4 == 2 tail
        MFMAP(A0, B0);
        MFMAP(A1, B1);
    }

    // 2-round chunked reduction + epilogue (round r -> rows r*32..r*32+31)
#pragma unroll
    for (int round = 0; round < 2; ++round) {
        if (round) __syncthreads();          // round-0 reads done before re-dump
#pragma unroll
        for (int rh = 0; rh < 2; ++rh) {
            const int rg = round * 2 + rh;
#pragma unroll
            for (int t = 0; t < 4; ++t)
#pragma unroll
                for (int r = 0; r < 4; ++r)
                    red[ws * RSZ2 + (rh * 16 + q4 + r) * RSTRIDE + t * 16 + l15]
                        = acc[rg][t][r];
        }
        __syncthreads();

        float g2[4][2];
#pragma unroll
        for (int G = 0; G < 4; ++G)
#pragma unroll
            for (int j = 0; j < 2; ++j) {
                const int cidx = r_row * RSTRIDE + G * 16 + r_u + j;
                g2[G][j] = red[0 * RSZ2 + cidx] + red[1 * RSZ2 + cidx]
                         + red[2 * RSZ2 + cidx] + red[3 * RSZ2 + cidx]
                         + bias[tn * 64 + G * 16 + r_u + j];
            }
        const f2 cold = round ? coldB : coldA;
        const int grow = tm * 64 + round * 32 + r_row;
        f2 cn; u32 hp = 0;
#pragma unroll
        for (int j = 0; j < 2; ++j) {
            const float I  = sigm(g2[0][j]);
            const float F  = sigm(g2[1][j]);
            const float Gg = tanh_f(g2[2][j]);
            const float O  = sigm(g2[3][j]);
            cn[j] = F * cold[j] + I * Gg;
            hp |= (u32)f2bf(O * tanh_f(cn[j])) << (j * 16);
        }
        *(f2*)&Cst[(size_t)grow * LDC + ecol] = cn;
        *(u32*)&Hdst[swz(KH_H, grow, ecol)] = hp;
    }
}

__global__ __launch_bounds__(256, 4) void cell_gemm(
    const u16* __restrict__ pA0, int kh0, int nk1,
    const u16* __restrict__ pA1, int kh1, int nk2,
    const u16* __restrict__ pB, int khB,
    const float* __restrict__ bias, float* __restrict__ Cst, u16* __restrict__ Hdst)
{
    __shared__ float red[4 * RSZ2];
    cell_body(blockIdx.x, pA0, kh0, nk1, pA1, kh1, nk2, pB, khB, bias, Cst, Hdst, red);
}

// ---- prompt pairing: blocks 0..511 cell1(t); 512..1023 cell0(t+1).
// With 34.3 KB LDS + 128 VGPR all 1024 blocks are co-resident (4 blocks/CU).
__global__ __launch_bounds__(256, 4) void pair_k(
    const u16* __restrict__ A0a, int kh0a, int nk1a,
    const u16* __restrict__ A1a, int kh1a, int nk2a,
    const u16* __restrict__ Ba, int khBa,
    const float* __restrict__ ba, float* __restrict__ Ca, u16* __restrict__ Ha,
    const u16* __restrict__ A0b, int kh0b, int nk1b,
    const u16* __restrict__ A1b, int kh1b, int nk2b,
    const u16* __restrict__ Bb, int khBb,
    const float* __restrict__ bb, float* __restrict__ Cb, u16* __restrict__ Hb)
{
    __shared__ float red[4 * RSZ2];
    if (blockIdx.x < 512)
        cell_body(blockIdx.x, A0a, kh0a, nk1a, A1a, kh1a, nk2a, Ba, khBa, ba, Ca, Ha, red);
    else
        cell_body(blockIdx.x - 512, A0b, kh0b, nk1b, A1b, kh1b, nk2b, Bb, khBb, bb, Cb, Hb, red);
}

// ---- Widened projection: 64 blocks, 64-row x 16-col tiles, 4-wave split-K
// over K=1024. Per-wave K order and 4-wave tree-add identical to the old
// 16-block proj_gemm -> bit-identical results, 4x the CU coverage.
// xl = xin + h1 @ Wout^T + bout; writes XL, XLbf, dout slot.
__global__ __launch_bounds__(256, 2) void proj64_k(
    const u16* __restrict__ pH1, const u16* __restrict__ pWo,
    const float* __restrict__ bout_,
    const float* __restrict__ xin, int ldxin,
    float* __restrict__ XL, u16* __restrict__ XLbf,
    float* __restrict__ dout, int slot)
{
    __shared__ float red[4 * RSZ];
    const int pb = blockIdx.x;           // 0..63
    const int tm = pb >> 3, cg = pb & 7; // rows tm*64.., cols cg*16..
    const int tid = threadIdx.x;
    const int lane = tid & 63, ws = tid >> 6;
    const int l15 = lane & 15, qd = lane >> 4;

    const u16* ap[4];
#pragma unroll
    for (int g = 0; g < 4; ++g)
        ap[g] = pH1 + (size_t)(tm * 4 + g) * (KH_H * 512) + lane * 8;
    const u16* bp = pWo + (size_t)cg * (KH_WO * 512) + lane * 8;

    f4 acc[4];
#pragma unroll
    for (int g = 0; g < 4; ++g) acc[g] = (f4)(0.f);

    for (int m = 0; m < 4; ++m) {
#pragma unroll
        for (int sh = 0; sh < 2; ++sh) {
            const int o = (((ws + m * 4) << 1) + sh) * 512;
            const bf8 Bv = ld8(bp + o);
#pragma unroll
            for (int g = 0; g < 4; ++g)
                acc[g] = MFMA16(ld8(ap[g] + o), Bv, acc[g]);
        }
    }

#pragma unroll
    for (int g = 0; g < 4; ++g)
#pragma unroll
        for (int r = 0; r < 4; ++r)
            red[ws * RSZ + (g * 16 + qd * 4 + r) * RSTRIDE + l15] = acc[g][r];
    __syncthreads();

    const int row = tid >> 2, c4 = (tid & 3) * 4;
    const int col = cg * 16 + c4;
    const int grow = tm * 64 + row;
    f4 s;
#pragma unroll
    for (int j = 0; j < 4; ++j) {
        const int cidx = row * RSTRIDE + c4 + j;
        s[j] = red[0 * RSZ + cidx] + red[1 * RSZ + cidx]
             + red[2 * RSZ + cidx] + red[3 * RSZ + cidx];
    }
    const f4 v = *(const f4*)&xin[(size_t)grow * ldxin + col] + s
                 + *(const f4*)&bout_[col];
    *(f4*)&XL[(size_t)grow * LDXL + col] = v;
    us4 b;
#pragma unroll
    for (int j = 0; j < 4; ++j) b[j] = f2bf(v[j]);
    *(us4*)&XLbf[swz(KH_XL, grow, col)] = b;
    *(f4*)&dout[(size_t)grow * OUTROW + slot * IN_ + col] = v;
}

// ---- Weight conversion: fp32 -> bf16 fragment-linear, gate-permuted rows,
// fused biases. One block per fragment; thread t writes u32 pair (coalesced).
__global__ void conv_w(const float* Wih0, const float* Whh0, const float* bih0, const float* bhh0,
                       const float* Wih1, const float* Whh1, const float* bih1, const float* bhh1,
                       const float* Wout,
                       u16* W0c, float* b0p, u16* W1c, float* b1p, u16* Woutb)
{
    const int bid = blockIdx.x, t = threadIdx.x;
    const int lane = t >> 2;              // fragment lane 0..63
    const int l15 = lane & 15, qd = lane >> 4;
    const int j0 = (t & 3) * 2;
    const int c0_ = qd * 8 + j0;

    if (bid < 9216) {                     // W0c: 256 rowgrps x 36 kh
        const int rg = bid / 36, kh = bid - rg * 36;
        const int p = rg * 16 + l15;
        const int rem = p & 63, G = rem >> 4, u = (p >> 6) * 16 + (rem & 15);
        const int src = G * H_ + u;
        float e0, e1;
        if (kh < 4) {
            e0 = Wih0[(size_t)src * IN_ + kh * 32 + c0_];
            e1 = Wih0[(size_t)src * IN_ + kh * 32 + c0_ + 1];
        } else {
            e0 = Whh0[(size_t)src * H_ + (kh - 4) * 32 + c0_];
            e1 = Whh0[(size_t)src * H_ + (kh - 4) * 32 + c0_ + 1];
        }
        ((u32*)W0c)[(size_t)bid * 256 + t] = (u32)f2bf(e0) | ((u32)f2bf(e1) << 16);
        if (kh == 0 && qd == 0 && j0 == 0) b0p[p] = bih0[src] + bhh0[src];
    } else if (bid < 25600) {             // W1c: 256 rowgrps x 64 kh
        const int x = bid - 9216;
        const int rg = x >> 6, kh = x & 63;
        const int p = rg * 16 + l15;
        const int rem = p & 63, G = rem >> 4, u = (p >> 6) * 16 + (rem & 15);
        const int src = G * H_ + u;
        float e0, e1;
        if (kh < 32) {
            e0 = Wih1[(size_t)src * H_ + kh * 32 + c0_];
            e1 = Wih1[(size_t)src * H_ + kh * 32 + c0_ + 1];
        } else {
            e0 = Whh1[(size_t)src * H_ + (kh - 32) * 32 + c0_];
            e1 = Whh1[(size_t)src * H_ + (kh - 32) * 32 + c0_ + 1];
        }
        ((u32*)W1c)[(size_t)x * 256 + t] = (u32)f2bf(e0) | ((u32)f2bf(e1) << 16);
        if (kh == 0 && qd == 0 && j0 == 0) b1p[p] = bih1[src] + bhh1[src];
    } else {                              // Woutb: 8 rowgrps x 32 kh
        const int x = bid - 25600;
        const int rg = x >> 5, kh = x & 31;
        const int r = rg * 16 + l15;
        const float e0 = Wout[(size_t)r * H_ + kh * 32 + c0_];
        const float e1 = Wout[(size_t)r * H_ + kh * 32 + c0_ + 1];
        ((u32*)Woutb)[(size_t)x * 256 + t] = (u32)f2bf(e0) | ((u32)f2bf(e1) << 16);
    }
}

// ---- Setup: zero states, x -> bf16 fragment-linear staging, x -> out[:,0:16] ----
__global__ void setup_k(const float* __restrict__ x, u16* __restrict__ Xb,
                        u16* H0, u16* H1, float* c0, float* c1,
                        float* __restrict__ dout)
{
    const int i = blockIdx.x * 256 + threadIdx.x;  // < 512*16*128
    const float v = x[i];
    const int r = i >> 11, col = i & 2047;
    Xb[swz(KH_X, r, col)] = f2bf(v);
    dout[(size_t)r * OUTROW + col] = v;
    if (i < B_ * H_) {
        H0[i] = 0; H1[i] = 0;
        const int rr = i >> 10, cc = i & 1023;
        c0[(size_t)rr * LDC + cc] = 0.f; c1[(size_t)rr * LDC + cc] = 0.f;
    }
}

extern "C" void kernel_launch(void* const* d_in, const int* in_sizes, int n_in,
                              void* d_out, int out_size, void* d_ws, size_t ws_size,
                              hipStream_t stream)
{
    const float* x    = (const float*)d_in[0];
    const float* Wih0 = (const float*)d_in[1];
    const float* Whh0 = (const float*)d_in[2];
    const float* bih0 = (const float*)d_in[3];
    const float* bhh0 = (const float*)d_in[4];
    const float* Wih1 = (const float*)d_in[5];
    const float* Whh1 = (const float*)d_in[6];
    const float* bih1 = (const float*)d_in[7];
    const float* bhh1 = (const float*)d_in[8];
    const float* Wout = (const float*)d_in[9];
    const float* bout = (const float*)d_in[10];
    float* dout = (float*)d_out;

    char* ws = (char*)d_ws;
    size_t off = 0;
    auto alloc = [&](size_t bytes) -> char* {
        char* p = ws + off; off += (bytes + 255) & ~(size_t)255; return p;
    };
    u16*  W0c   = (u16*)alloc((size_t)9216 * 1024);
    u16*  W1c   = (u16*)alloc((size_t)16384 * 1024);
    u16*  Woutb = (u16*)alloc((size_t)256 * 1024);
    float* b0p  = (float*)alloc(4096 * 4);
    float* b1p  = (float*)alloc(4096 * 4);
    u16*  Xb    = (u16*)alloc((size_t)2048 * 1024);
    u16*  H0b[2]; H0b[0] = (u16*)alloc((size_t)1024 * 1024); H0b[1] = (u16*)alloc((size_t)1024 * 1024);
    u16*  H1b[2]; H1b[0] = (u16*)alloc((size_t)1024 * 1024); H1b[1] = (u16*)alloc((size_t)1024 * 1024);
    float* c0   = (float*)alloc((size_t)B_ * LDC * 4);
    float* c1   = (float*)alloc((size_t)B_ * LDC * 4);
    float* XL   = (float*)alloc((size_t)B_ * LDXL * 4);
    u16*  XLbf  = (u16*)alloc((size_t)128 * 1024);

    conv_w<<<25856, 256, 0, stream>>>(Wih0, Whh0, bih0, bhh0,
                                      Wih1, Whh1, bih1, bhh1, Wout,
                                      W0c, b0p, W1c, b1p, Woutb);
    setup_k<<<4096, 256, 0, stream>>>(x, Xb, H0b[0], H1b[0], c0, c1, dout);

    // ---- prompt: cell0(0); 15 x [cell1(t) || cell0(t+1)]; cell1(15); proj(15)
    int p = 0;
    cell_gemm<<<512, 256, 0, stream>>>(Xb, KH_X, 2, H0b[0], KH_H, 16,
                                       W0c, KH_W0, b0p, c0, H0b[1]);
    for (int g = 0; g < 15; ++g) {
        pair_k<<<1024, 256, 0, stream>>>(
            H0b[1 - p], KH_H, 16, H1b[p], KH_H, 16, W1c, KH_W1, b1p, c1, H1b[1 - p],
            Xb + (size_t)(g + 1) * 2048, KH_X, 2, H0b[1 - p], KH_H, 16,
            W0c, KH_W0, b0p, c0, H0b[p]);
        p ^= 1;
    }
    // here p = 1: cell0(15) wrote H0b[0]; latest H1 = H1b[1]
    cell_gemm<<<512, 256, 0, stream>>>(H0b[0], KH_H, 16, H1b[1], KH_H, 16,
                                       W1c, KH_W1, b1p, c1, H1b[0]);   // h1(15)
    proj64_k<<<64, 256, 0, stream>>>(H1b[0], Woutb, bout,
                                     x + 15 * IN_, L_ * IN_, XL, XLbf, dout, 16);

    // ---- rollout: 63 steps, latest state H0 = H0b[0], H1 = H1b[0]
    p = 0;
    for (int g = 16; g < 79; ++g) {
        cell_gemm<<<512, 256, 0, stream>>>(XLbf, KH_XL, 2, H0b[p], KH_H, 16,
                                           W0c, KH_W0, b0p, c0, H0b[1 - p]);
        cell_gemm<<<512, 256, 0, stream>>>(H0b[1 - p], KH_H, 16, H1b[p], KH_H, 16,
                                           W1c, KH_W1, b1p, c1, H1b[1 - p]);
        const int s = g - 15;            // 1..63 -> out slot 16+s
        proj64_k<<<64, 256, 0, stream>>>(H1b[1 - p], Woutb, bout,
                                         XL, LDXL, XL, XLbf, dout, 16 + s);
        p ^= 1;
    }
}

// Round 8
// 2412.791 us; speedup vs baseline: 6.5219x; 6.5219x over previous
//
#include <hip/hip_runtime.h>

#define B_    512
#define L_    16
#define IN_   128
#define H_    1024
#define T_    64
#define OUTROW 10240   /* (L_+T_)*IN_ */

#define LDC   1040     /* c state fp32 row stride (padded) */
#define LDXL  144      /* XL fp32 row stride */
#define RSTRIDE 67     /* padded fp32 row stride in LDS reduction buffer */
#define RSZ   (64 * RSTRIDE)

/* ---- fragment-linear bf16 operand layout ----
   fragment = 16 rows x 32 k-cols = 1024B, lane-linear:
     elem(row,k) @ u16 index  frag*512 + ((k&31)>>3)*128 + (row&15)*8 + (k&7)
     frag = (row>>4)*KH + (k>>5),  KH = K/32 */
#define KH_X  64   /* Xb   : 2048 cols */
#define KH_H  32   /* H    : 1024 cols */
#define KH_XL 4    /* XLbf : 128 cols  */
#define KH_W0 36   /* W0c  : 1152      */
#define KH_W1 64   /* W1c  : 2048      */
#define KH_WO 32   /* Woutb: 1024      */

typedef __attribute__((ext_vector_type(8))) short bf8;
typedef __attribute__((ext_vector_type(4))) float f4;
typedef __attribute__((ext_vector_type(4))) unsigned short us4;
typedef unsigned short u16;
typedef unsigned int   u32;

#define MFMA16(a, b, c) __builtin_amdgcn_mfma_f32_16x16x32_bf16(a, b, c, 0, 0, 0)

__device__ __forceinline__ u16 f2bf(float f) {
    u32 u = __builtin_bit_cast(u32, f);
    u32 r = (u + 0x7fffu + ((u >> 16) & 1u)) >> 16;
    return (u16)r;
}
__device__ __forceinline__ float sigm(float x) { return 1.f / (1.f + __expf(-x)); }
__device__ __forceinline__ float tanh_f(float x) {
    float ax = fabsf(x);
    float e = __expf(-2.f * ax);
    float t = (1.f - e) / (1.f + e);
    return x < 0.f ? -t : t;
}
__device__ __forceinline__ bf8 ld8(const u16* p) { return *(const bf8*)p; }

__device__ __forceinline__ size_t swz(int kh_stride, int row, int k) {
    return ((size_t)(row >> 4) * kh_stride + (k >> 5)) * 512
           + ((k & 31) >> 3) * 128 + (row & 15) * 8 + (k & 7);
}

// 16-MFMA pack on one 32-col fragment set
#define MFMAP(AS, BS)                                                       \
  do {                                                                      \
    _Pragma("unroll")                                                       \
    for (int g_ = 0; g_ < 4; ++g_)                                          \
      _Pragma("unroll")                                                     \
      for (int t_ = 0; t_ < 4; ++t_)                                        \
        acc[g_][t_] = MFMA16(AS[g_], BS[t_], acc[g_][t_]);                  \
  } while (0)

// Load fragment set for 32-col phase PH of this wave's sequence.
#define LOADP_CELL(AS, BS, PH)                                              \
  do {                                                                      \
    const int kt_ = ws + (((PH) >> 1) << 2);                                \
    const int s_  = (PH) & 1;                                               \
    const bool ix_ = kt_ < nk1;                                             \
    const int oA_ = (((ix_ ? kt_ : kt_ - nk1) << 1) + s_) * 512;            \
    const int oB_ = ((kt_ << 1) + s_) * 512;                                \
    _Pragma("unroll")                                                       \
    for (int g_ = 0; g_ < 4; ++g_)                                          \
      AS[g_] = ld8((ix_ ? apx[g_] : aph[g_]) + oA_);                        \
    _Pragma("unroll")                                                       \
    for (int t_ = 0; t_ < 4; ++t_) BS[t_] = ld8(bp[t_] + oB_);              \
  } while (0)

// ---- LSTM cell body: 4-wave split-K GEMM with 4-deep (3-phase-ahead)
// register pipeline + LDS reduction + fused cell epilogue.
// Needs the full 128-VGPR budget: NEVER raise launch_bounds past (256,2) —
// round-7 measured: (256,4) caps VGPR at 64 -> spills -> 6x regression.
__device__ __forceinline__ void cell_body(int bid,
    const u16* __restrict__ pA0, int kh0, int nk1,
    const u16* __restrict__ pA1, int kh1, int nk2,
    const u16* __restrict__ pB, int khB,
    const float* __restrict__ bias, float* __restrict__ Cst,
    u16* __restrict__ Hdst, float* __restrict__ red)
{
    const int tn = (bid & 7) * 8 + ((bid >> 3) & 7);   // XCD-pins tn slice
    const int tm = bid >> 6;
    const int tid = threadIdx.x;
    const int lane = tid & 63, ws = tid >> 6;
    const int l15 = lane & 15, qd = lane >> 4, q4 = qd * 4;

    const int erow = ws * 16 + l15;
    const int grow = tm * 64 + erow;
    const int colb = tn * 16 + q4;
    const f4 cold = *(const f4*)&Cst[(size_t)grow * LDC + colb];

    f4 acc[4][4];
#pragma unroll
    for (int i = 0; i < 4; ++i)
#pragma unroll
        for (int j = 0; j < 4; ++j) acc[i][j] = (f4)(0.f);

    const u16* bp[4];
#pragma unroll
    for (int t = 0; t < 4; ++t)
        bp[t] = pB + (size_t)(tn * 4 + t) * khB * 512 + lane * 8;
    const u16* apx[4];
    const u16* aph[4];
#pragma unroll
    for (int g = 0; g < 4; ++g) {
        apx[g] = pA0 + (size_t)(tm * 4 + g) * kh0 * 512 + lane * 8;
        aph[g] = pA1 + (size_t)(tm * 4 + g) * kh1 * 512 + lane * 8;
    }

    const int nk  = nk1 + nk2;
    const int myn = (nk - ws + 3) >> 2;
    const int nph = myn * 2;                // even, >= 8 for all shapes used

    bf8 A0[4], B0[4], A1[4], B1[4], A2[4], B2[4], A3[4], B3[4];
    LOADP_CELL(A0, B0, 0);
    LOADP_CELL(A1, B1, 1);
    LOADP_CELL(A2, B2, 2);
    int ph = 0;
    for (; ph + 4 <= nph; ph += 4) {
        LOADP_CELL(A3, B3, ph + 3);
        MFMAP(A0, B0);
        if (ph + 4 < nph) LOADP_CELL(A0, B0, ph + 4);
        MFMAP(A1, B1);
        if (ph + 5 < nph) LOADP_CELL(A1, B1, ph + 5);
        MFMAP(A2, B2);
        if (ph + 6 < nph) LOADP_CELL(A2, B2, ph + 6);
        MFMAP(A3, B3);
    }
    if (ph < nph) {                          // nph % 4 == 2 tail
        MFMAP(A0, B0);
        MFMAP(A1, B1);
    }

#pragma unroll
    for (int rg = 0; rg < 4; ++rg)
#pragma unroll
        for (int t = 0; t < 4; ++t)
#pragma unroll
            for (int r = 0; r < 4; ++r)
                red[ws * RSZ + (rg * 16 + q4 + r) * RSTRIDE + t * 16 + l15] = acc[rg][t][r];
    __syncthreads();

    f4 gs[4];
#pragma unroll
    for (int G = 0; G < 4; ++G) {
        f4 s;
#pragma unroll
        for (int j = 0; j < 4; ++j) {
            const int cidx = erow * RSTRIDE + G * 16 + q4 + j;
            s[j] = red[0 * RSZ + cidx] + red[1 * RSZ + cidx]
                 + red[2 * RSZ + cidx] + red[3 * RSZ + cidx];
        }
        gs[G] = s + *(const f4*)&bias[tn * 64 + G * 16 + q4];
    }
    f4 cn; us4 h4;
#pragma unroll
    for (int j = 0; j < 4; ++j) {
        const float I  = sigm(gs[0][j]);
        const float F  = sigm(gs[1][j]);
        const float Gg = tanh_f(gs[2][j]);
        const float O  = sigm(gs[3][j]);
        cn[j] = F * cold[j] + I * Gg;
        h4[j] = f2bf(O * tanh_f(cn[j]));
    }
    *(f4*)&Cst[(size_t)grow * LDC + colb] = cn;
    *(us4*)&Hdst[swz(KH_H, grow, colb)] = h4;
}

__global__ __launch_bounds__(256, 2) void cell_gemm(
    const u16* __restrict__ pA0, int kh0, int nk1,
    const u16* __restrict__ pA1, int kh1, int nk2,
    const u16* __restrict__ pB, int khB,
    const float* __restrict__ bias, float* __restrict__ Cst, u16* __restrict__ Hdst)
{
    __shared__ float red[4 * RSZ];
    cell_body(blockIdx.x, pA0, kh0, nk1, pA1, kh1, nk2, pB, khB, bias, Cst, Hdst, red);
}

// ---- prompt pairing: blocks 0..511 cell1(t); 512..1023 cell0(t+1). Both read
// only prior-dispatch data and write disjoint buffers.
__global__ __launch_bounds__(256, 2) void pair_k(
    const u16* __restrict__ A0a, int kh0a, int nk1a,
    const u16* __restrict__ A1a, int kh1a, int nk2a,
    const u16* __restrict__ Ba, int khBa,
    const float* __restrict__ ba, float* __restrict__ Ca, u16* __restrict__ Ha,
    const u16* __restrict__ A0b, int kh0b, int nk1b,
    const u16* __restrict__ A1b, int kh1b, int nk2b,
    const u16* __restrict__ Bb, int khBb,
    const float* __restrict__ bb, float* __restrict__ Cb, u16* __restrict__ Hb)
{
    __shared__ float red[4 * RSZ];
    if (blockIdx.x < 512)
        cell_body(blockIdx.x, A0a, kh0a, nk1a, A1a, kh1a, nk2a, Ba, khBa, ba, Ca, Ha, red);
    else
        cell_body(blockIdx.x - 512, A0b, kh0b, nk1b, A1b, kh1b, nk2b, Bb, khBb, bb, Cb, Hb, red);
}

// ---- Widened projection: 64 blocks, 64-row x 16-col tiles, 4-wave split-K
// over K=1024 (harness-verified round 7). Per-wave K order and 4-wave
// tree-add identical to the old 16-block proj -> bit-identical results,
// 4x the CU coverage. xl = xin + h1 @ Wout^T + bout.
__global__ __launch_bounds__(256, 2) void proj64_k(
    const u16* __restrict__ pH1, const u16* __restrict__ pWo,
    const float* __restrict__ bout_,
    const float* __restrict__ xin, int ldxin,
    float* __restrict__ XL, u16* __restrict__ XLbf,
    float* __restrict__ dout, int slot)
{
    __shared__ float red[4 * RSZ];
    const int pb = blockIdx.x;           // 0..63
    const int tm = pb >> 3, cg = pb & 7; // rows tm*64.., cols cg*16..
    const int tid = threadIdx.x;
    const int lane = tid & 63, ws = tid >> 6;
    const int l15 = lane & 15, qd = lane >> 4;

    const u16* ap[4];
#pragma unroll
    for (int g = 0; g < 4; ++g)
        ap[g] = pH1 + (size_t)(tm * 4 + g) * (KH_H * 512) + lane * 8;
    const u16* bp = pWo + (size_t)cg * (KH_WO * 512) + lane * 8;

    f4 acc[4];
#pragma unroll
    for (int g = 0; g < 4; ++g) acc[g] = (f4)(0.f);

    for (int m = 0; m < 4; ++m) {
#pragma unroll
        for (int sh = 0; sh < 2; ++sh) {
            const int o = (((ws + m * 4) << 1) + sh) * 512;
            const bf8 Bv = ld8(bp + o);
#pragma unroll
            for (int g = 0; g < 4; ++g)
                acc[g] = MFMA16(ld8(ap[g] + o), Bv, acc[g]);
        }
    }

#pragma unroll
    for (int g = 0; g < 4; ++g)
#pragma unroll
        for (int r = 0; r < 4; ++r)
            red[ws * RSZ + (g * 16 + qd * 4 + r) * RSTRIDE + l15] = acc[g][r];
    __syncthreads();

    const int row = tid >> 2, c4 = (tid & 3) * 4;
    const int col = cg * 16 + c4;
    const int grow = tm * 64 + row;
    f4 s;
#pragma unroll
    for (int j = 0; j < 4; ++j) {
        const int cidx = row * RSTRIDE + c4 + j;
        s[j] = red[0 * RSZ + cidx] + red[1 * RSZ + cidx]
             + red[2 * RSZ + cidx] + red[3 * RSZ + cidx];
    }
    const f4 v = *(const f4*)&xin[(size_t)grow * ldxin + col] + s
                 + *(const f4*)&bout_[col];
    *(f4*)&XL[(size_t)grow * LDXL + col] = v;
    us4 b;
#pragma unroll
    for (int j = 0; j < 4; ++j) b[j] = f2bf(v[j]);
    *(us4*)&XLbf[swz(KH_XL, grow, col)] = b;
    *(f4*)&dout[(size_t)grow * OUTROW + slot * IN_ + col] = v;
}

// ---- Weight conversion: fp32 -> bf16 fragment-linear, gate-permuted rows,
// fused biases. One block per fragment; thread t writes u32 pair (coalesced).
__global__ void conv_w(const float* Wih0, const float* Whh0, const float* bih0, const float* bhh0,
                       const float* Wih1, const float* Whh1, const float* bih1, const float* bhh1,
                       const float* Wout,
                       u16* W0c, float* b0p, u16* W1c, float* b1p, u16* Woutb)
{
    const int bid = blockIdx.x, t = threadIdx.x;
    const int lane = t >> 2;              // fragment lane 0..63
    const int l15 = lane & 15, qd = lane >> 4;
    const int j0 = (t & 3) * 2;
    const int c0_ = qd * 8 + j0;

    if (bid < 9216) {                     // W0c: 256 rowgrps x 36 kh
        const int rg = bid / 36, kh = bid - rg * 36;
        const int p = rg * 16 + l15;
        const int rem = p & 63, G = rem >> 4, u = (p >> 6) * 16 + (rem & 15);
        const int src = G * H_ + u;
        float e0, e1;
        if (kh < 4) {
            e0 = Wih0[(size_t)src * IN_ + kh * 32 + c0_];
            e1 = Wih0[(size_t)src * IN_ + kh * 32 + c0_ + 1];
        } else {
            e0 = Whh0[(size_t)src * H_ + (kh - 4) * 32 + c0_];
            e1 = Whh0[(size_t)src * H_ + (kh - 4) * 32 + c0_ + 1];
        }
        ((u32*)W0c)[(size_t)bid * 256 + t] = (u32)f2bf(e0) | ((u32)f2bf(e1) << 16);
        if (kh == 0 && qd == 0 && j0 == 0) b0p[p] = bih0[src] + bhh0[src];
    } else if (bid < 25600) {             // W1c: 256 rowgrps x 64 kh
        const int x = bid - 9216;
        const int rg = x >> 6, kh = x & 63;
        const int p = rg * 16 + l15;
        const int rem = p & 63, G = rem >> 4, u = (p >> 6) * 16 + (rem & 15);
        const int src = G * H_ + u;
        float e0, e1;
        if (kh < 32) {
            e0 = Wih1[(size_t)src * H_ + kh * 32 + c0_];
            e1 = Wih1[(size_t)src * H_ + kh * 32 + c0_ + 1];
        } else {
            e0 = Whh1[(size_t)src * H_ + (kh - 32) * 32 + c0_];
            e1 = Whh1[(size_t)src * H_ + (kh - 32) * 32 + c0_ + 1];
        }
        ((u32*)W1c)[(size_t)x * 256 + t] = (u32)f2bf(e0) | ((u32)f2bf(e1) << 16);
        if (kh == 0 && qd == 0 && j0 == 0) b1p[p] = bih1[src] + bhh1[src];
    } else {                              // Woutb: 8 rowgrps x 32 kh
        const int x = bid - 25600;
        const int rg = x >> 5, kh = x & 31;
        const int r = rg * 16 + l15;
        const float e0 = Wout[(size_t)r * H_ + kh * 32 + c0_];
        const float e1 = Wout[(size_t)r * H_ + kh * 32 + c0_ + 1];
        ((u32*)Woutb)[(size_t)x * 256 + t] = (u32)f2bf(e0) | ((u32)f2bf(e1) << 16);
    }
}

// ---- Setup: zero states, x -> bf16 fragment-linear staging, x -> out[:,0:16] ----
__global__ void setup_k(const float* __restrict__ x, u16* __restrict__ Xb,
                        u16* H0, u16* H1, float* c0, float* c1,
                        float* __restrict__ dout)
{
    const int i = blockIdx.x * 256 + threadIdx.x;  // < 512*16*128
    const float v = x[i];
    const int r = i >> 11, col = i & 2047;
    Xb[swz(KH_X, r, col)] = f2bf(v);
    dout[(size_t)r * OUTROW + col] = v;
    if (i < B_ * H_) {
        H0[i] = 0; H1[i] = 0;
        const int rr = i >> 10, cc = i & 1023;
        c0[(size_t)rr * LDC + cc] = 0.f; c1[(size_t)rr * LDC + cc] = 0.f;
    }
}

extern "C" void kernel_launch(void* const* d_in, const int* in_sizes, int n_in,
                              void* d_out, int out_size, void* d_ws, size_t ws_size,
                              hipStream_t stream)
{
    const float* x    = (const float*)d_in[0];
    const float* Wih0 = (const float*)d_in[1];
    const float* Whh0 = (const float*)d_in[2];
    const float* bih0 = (const float*)d_in[3];
    const float* bhh0 = (const float*)d_in[4];
    const float* Wih1 = (const float*)d_in[5];
    const float* Whh1 = (const float*)d_in[6];
    const float* bih1 = (const float*)d_in[7];
    const float* bhh1 = (const float*)d_in[8];
    const float* Wout = (const float*)d_in[9];
    const float* bout = (const float*)d_in[10];
    float* dout = (float*)d_out;

    char* ws = (char*)d_ws;
    size_t off = 0;
    auto alloc = [&](size_t bytes) -> char* {
        char* p = ws + off; off += (bytes + 255) & ~(size_t)255; return p;
    };
    u16*  W0c   = (u16*)alloc((size_t)9216 * 1024);
    u16*  W1c   = (u16*)alloc((size_t)16384 * 1024);
    u16*  Woutb = (u16*)alloc((size_t)256 * 1024);
    float* b0p  = (float*)alloc(4096 * 4);
    float* b1p  = (float*)alloc(4096 * 4);
    u16*  Xb    = (u16*)alloc((size_t)2048 * 1024);
    u16*  H0b[2]; H0b[0] = (u16*)alloc((size_t)1024 * 1024); H0b[1] = (u16*)alloc((size_t)1024 * 1024);
    u16*  H1b[2]; H1b[0] = (u16*)alloc((size_t)1024 * 1024); H1b[1] = (u16*)alloc((size_t)1024 * 1024);
    float* c0   = (float*)alloc((size_t)B_ * LDC * 4);
    float* c1   = (float*)alloc((size_t)B_ * LDC * 4);
    float* XL   = (float*)alloc((size_t)B_ * LDXL * 4);
    u16*  XLbf  = (u16*)alloc((size_t)128 * 1024);

    conv_w<<<25856, 256, 0, stream>>>(Wih0, Whh0, bih0, bhh0,
                                      Wih1, Whh1, bih1, bhh1, Wout,
                                      W0c, b0p, W1c, b1p, Woutb);
    setup_k<<<4096, 256, 0, stream>>>(x, Xb, H0b[0], H1b[0], c0, c1, dout);

    // ---- prompt: cell0(0); 15 x [cell1(t) || cell0(t+1)]; cell1(15); proj(15)
    int p = 0;
    cell_gemm<<<512, 256, 0, stream>>>(Xb, KH_X, 2, H0b[0], KH_H, 16,
                                       W0c, KH_W0, b0p, c0, H0b[1]);
    for (int g = 0; g < 15; ++g) {
        pair_k<<<1024, 256, 0, stream>>>(
            H0b[1 - p], KH_H, 16, H1b[p], KH_H, 16, W1c, KH_W1, b1p, c1, H1b[1 - p],
            Xb + (size_t)(g + 1) * 2048, KH_X, 2, H0b[1 - p], KH_H, 16,
            W0c, KH_W0, b0p, c0, H0b[p]);
        p ^= 1;
    }
    // here p = 1: cell0(15) wrote H0b[0]; latest H1 = H1b[1]
    cell_gemm<<<512, 256, 0, stream>>>(H0b[0], KH_H, 16, H1b[1], KH_H, 16,
                                       W1c, KH_W1, b1p, c1, H1b[0]);   // h1(15)
    proj64_k<<<64, 256, 0, stream>>>(H1b[0], Woutb, bout,
                                     x + 15 * IN_, L_ * IN_, XL, XLbf, dout, 16);

    // ---- rollout: 63 steps, latest state H0 = H0b[0], H1 = H1b[0]
    p = 0;
    for (int g = 16; g < 79; ++g) {
        cell_gemm<<<512, 256, 0, stream>>>(XLbf, KH_XL, 2, H0b[p], KH_H, 16,
                                           W0c, KH_W0, b0p, c0, H0b[1 - p]);
        cell_gemm<<<512, 256, 0, stream>>>(H0b[1 - p], KH_H, 16, H1b[p], KH_H, 16,
                                           W1c, KH_W1, b1p, c1, H1b[1 - p]);
        const int s = g - 15;            // 1..63 -> out slot 16+s
        proj64_k<<<64, 256, 0, stream>>>(H1b[1 - p], Woutb, bout,
                                         XL, LDXL, XL, XLbf, dout, 16 + s);
        p ^= 1;
    }
}

// Round 9
// 2345.537 us; speedup vs baseline: 6.7089x; 1.0287x over previous
//
#include <hip/hip_runtime.h>

#define B_    512
#define L_    16
#define IN_   128
#define H_    1024
#define T_    64
#define OUTROW 10240   /* (L_+T_)*IN_ */

#define LDC   1040     /* c state fp32 row stride (padded) */
#define LDXL  144      /* XL fp32 row stride */
#define RSTRIDE 67     /* padded fp32 row stride in LDS reduction buffer */
#define RSZ   (64 * RSTRIDE)

/* ---- fragment-linear bf16 operand layout ----
   fragment = 16 rows x 32 k-cols = 1024B, lane-linear:
     elem(row,k) @ u16 index  frag*512 + ((k&31)>>3)*128 + (row&15)*8 + (k&7)
     frag = (row>>4)*KH + (k>>5),  KH = K/32 */
#define KH_X  64   /* Xb   : 2048 cols */
#define KH_H  32   /* H    : 1024 cols */
#define KH_XL 4    /* XLbf : 128 cols  */
#define KH_W0 36   /* W0c  : 1152 (x kh 0..3, h kh 4..35) */
#define KH_W1 64   /* W1c  : 2048      */
#define KH_WO 32   /* Woutb: 1024      */

typedef __attribute__((ext_vector_type(8))) short bf8;
typedef __attribute__((ext_vector_type(4))) float f4;
typedef __attribute__((ext_vector_type(4))) unsigned short us4;
typedef unsigned short u16;
typedef unsigned int   u32;

#define MFMA16(a, b, c) __builtin_amdgcn_mfma_f32_16x16x32_bf16(a, b, c, 0, 0, 0)

__device__ __forceinline__ u16 f2bf(float f) {
    u32 u = __builtin_bit_cast(u32, f);
    u32 r = (u + 0x7fffu + ((u >> 16) & 1u)) >> 16;
    return (u16)r;
}
__device__ __forceinline__ float sigm(float x) { return 1.f / (1.f + __expf(-x)); }
__device__ __forceinline__ float tanh_f(float x) {
    float ax = fabsf(x);
    float e = __expf(-2.f * ax);
    float t = (1.f - e) / (1.f + e);
    return x < 0.f ? -t : t;
}
__device__ __forceinline__ bf8 ld8(const u16* p) { return *(const bf8*)p; }

// ---- LLC-coherent handoff primitives (intra-dispatch, NO cache invalidation):
// sc0 sc1 = bypass L1+L2, read/write the die-level LLC directly. Producers
// drain vmcnt before a RELAXED flag-add (also at LLC); consumers read flagged
// data ONLY via these loads, so no acquire fence (and no L2 inv) is needed.
__device__ __forceinline__ bf8 ld8_cc(const u16* p) {
    bf8 r;
    asm volatile("global_load_dwordx4 %0, %1, off sc0 sc1"
                 : "=v"(r) : "v"(p) : "memory");
    return r;
}
__device__ __forceinline__ void st8_cc(u16* p, us4 v) {
    asm volatile("global_store_dwordx2 %0, %1, off sc0 sc1"
                 :: "v"(p), "v"(v) : "memory");
}

__device__ __forceinline__ size_t swz(int kh_stride, int row, int k) {
    return ((size_t)(row >> 4) * kh_stride + (k >> 5)) * 512
           + ((k & 31) >> 3) * 128 + (row & 15) * 8 + (k & 7);
}

// 16-MFMA pack on one 32-col fragment set
#define MFMAP(AS, BS)                                                       \
  do {                                                                      \
    _Pragma("unroll")                                                       \
    for (int g_ = 0; g_ < 4; ++g_)                                          \
      _Pragma("unroll")                                                     \
      for (int t_ = 0; t_ < 4; ++t_)                                        \
        acc[g_][t_] = MFMA16(AS[g_], BS[t_], acc[g_][t_]);                  \
  } while (0)

// Load fragment set for 32-col phase PH of this wave's sequence.
#define LOADP_CELL(AS, BS, PH)                                              \
  do {                                                                      \
    const int kt_ = ws + (((PH) >> 1) << 2);                                \
    const int s_  = (PH) & 1;                                               \
    const bool ix_ = kt_ < nk1;                                             \
    const int oA_ = (((ix_ ? kt_ : kt_ - nk1) << 1) + s_) * 512;            \
    const int oB_ = ((kt_ << 1) + s_) * 512;                                \
    _Pragma("unroll")                                                       \
    for (int g_ = 0; g_ < 4; ++g_)                                          \
      AS[g_] = ld8((ix_ ? apx[g_] : aph[g_]) + oA_);                        \
    _Pragma("unroll")                                                       \
    for (int t_ = 0; t_ < 4; ++t_) BS[t_] = ld8(bp[t_] + oB_);              \
  } while (0)

// ---- LSTM cell body: 4-wave split-K GEMM with 4-deep (3-phase-ahead)
// register pipeline + LDS reduction + fused cell epilogue.
// Needs the full 128-VGPR budget: NEVER raise launch_bounds past (256,2) —
// round-7 measured: (256,4) caps VGPR at 64 -> spills -> 6x regression.
__device__ __forceinline__ void cell_body(int bid,
    const u16* __restrict__ pA0, int kh0, int nk1,
    const u16* __restrict__ pA1, int kh1, int nk2,
    const u16* __restrict__ pB, int khB,
    const float* __restrict__ bias, float* __restrict__ Cst,
    u16* __restrict__ Hdst, float* __restrict__ red)
{
    const int tn = (bid & 7) * 8 + ((bid >> 3) & 7);   // XCD-pins tn slice
    const int tm = bid >> 6;
    const int tid = threadIdx.x;
    const int lane = tid & 63, ws = tid >> 6;
    const int l15 = lane & 15, qd = lane >> 4, q4 = qd * 4;

    const int erow = ws * 16 + l15;
    const int grow = tm * 64 + erow;
    const int colb = tn * 16 + q4;
    const f4 cold = *(const f4*)&Cst[(size_t)grow * LDC + colb];

    f4 acc[4][4];
#pragma unroll
    for (int i = 0; i < 4; ++i)
#pragma unroll
        for (int j = 0; j < 4; ++j) acc[i][j] = (f4)(0.f);

    const u16* bp[4];
#pragma unroll
    for (int t = 0; t < 4; ++t)
        bp[t] = pB + (size_t)(tn * 4 + t) * khB * 512 + lane * 8;
    const u16* apx[4];
    const u16* aph[4];
#pragma unroll
    for (int g = 0; g < 4; ++g) {
        apx[g] = pA0 + (size_t)(tm * 4 + g) * kh0 * 512 + lane * 8;
        aph[g] = pA1 + (size_t)(tm * 4 + g) * kh1 * 512 + lane * 8;
    }

    const int nk  = nk1 + nk2;
    const int myn = (nk - ws + 3) >> 2;
    const int nph = myn * 2;                // even, >= 8 for all shapes used

    bf8 A0[4], B0[4], A1[4], B1[4], A2[4], B2[4], A3[4], B3[4];
    LOADP_CELL(A0, B0, 0);
    LOADP_CELL(A1, B1, 1);
    LOADP_CELL(A2, B2, 2);
    int ph = 0;
    for (; ph + 4 <= nph; ph += 4) {
        LOADP_CELL(A3, B3, ph + 3);
        MFMAP(A0, B0);
        if (ph + 4 < nph) LOADP_CELL(A0, B0, ph + 4);
        MFMAP(A1, B1);
        if (ph + 5 < nph) LOADP_CELL(A1, B1, ph + 5);
        MFMAP(A2, B2);
        if (ph + 6 < nph) LOADP_CELL(A2, B2, ph + 6);
        MFMAP(A3, B3);
    }
    if (ph < nph) {                          // nph % 4 == 2 tail
        MFMAP(A0, B0);
        MFMAP(A1, B1);
    }

#pragma unroll
    for (int rg = 0; rg < 4; ++rg)
#pragma unroll
        for (int t = 0; t < 4; ++t)
#pragma unroll
            for (int r = 0; r < 4; ++r)
                red[ws * RSZ + (rg * 16 + q4 + r) * RSTRIDE + t * 16 + l15] = acc[rg][t][r];
    __syncthreads();

    f4 gs[4];
#pragma unroll
    for (int G = 0; G < 4; ++G) {
        f4 s;
#pragma unroll
        for (int j = 0; j < 4; ++j) {
            const int cidx = erow * RSTRIDE + G * 16 + q4 + j;
            s[j] = red[0 * RSZ + cidx] + red[1 * RSZ + cidx]
                 + red[2 * RSZ + cidx] + red[3 * RSZ + cidx];
        }
        gs[G] = s + *(const f4*)&bias[tn * 64 + G * 16 + q4];
    }
    f4 cn; us4 h4;
#pragma unroll
    for (int j = 0; j < 4; ++j) {
        const float I  = sigm(gs[0][j]);
        const float F  = sigm(gs[1][j]);
        const float Gg = tanh_f(gs[2][j]);
        const float O  = sigm(gs[3][j]);
        cn[j] = F * cold[j] + I * Gg;
        h4[j] = f2bf(O * tanh_f(cn[j]));
    }
    *(f4*)&Cst[(size_t)grow * LDC + colb] = cn;
    *(us4*)&Hdst[swz(KH_H, grow, colb)] = h4;
}

__global__ __launch_bounds__(256, 2) void cell_gemm(
    const u16* __restrict__ pA0, int kh0, int nk1,
    const u16* __restrict__ pA1, int kh1, int nk2,
    const u16* __restrict__ pB, int khB,
    const float* __restrict__ bias, float* __restrict__ Cst, u16* __restrict__ Hdst)
{
    __shared__ float red[4 * RSZ];
    cell_body(blockIdx.x, pA0, kh0, nk1, pA1, kh1, nk2, pB, khB, bias, Cst, Hdst, red);
}

// ---- prompt pairing: blocks 0..511 cell1(t); 512..1023 cell0(t+1). Both read
// only prior-dispatch data and write disjoint buffers.
__global__ __launch_bounds__(256, 2) void pair_k(
    const u16* __restrict__ A0a, int kh0a, int nk1a,
    const u16* __restrict__ A1a, int kh1a, int nk2a,
    const u16* __restrict__ Ba, int khBa,
    const float* __restrict__ ba, float* __restrict__ Ca, u16* __restrict__ Ha,
    const u16* __restrict__ A0b, int kh0b, int nk1b,
    const u16* __restrict__ A1b, int kh1b, int nk2b,
    const u16* __restrict__ Bb, int khBb,
    const float* __restrict__ bb, float* __restrict__ Cb, u16* __restrict__ Hb)
{
    __shared__ float red[4 * RSZ];
    if (blockIdx.x < 512)
        cell_body(blockIdx.x, A0a, kh0a, nk1a, A1a, kh1a, nk2a, Ba, khBa, ba, Ca, Ha, red);
    else
        cell_body(blockIdx.x - 512, A0b, kh0b, nk1b, A1b, kh1b, nk2b, Bb, khBb, bb, Cb, Hb, red);
}

// ---- Widened projection (standalone; used for the FINAL slot 79 only):
// 64 blocks, 64-row x 16-col tiles, 4-wave split-K over K=1024.
__global__ __launch_bounds__(256, 2) void proj64_k(
    const u16* __restrict__ pH1, const u16* __restrict__ pWo,
    const float* __restrict__ bout_,
    const float* __restrict__ xin, int ldxin,
    float* __restrict__ XL, u16* __restrict__ XLbf,
    float* __restrict__ dout, int slot)
{
    __shared__ float red[4 * RSZ];
    const int pb = blockIdx.x;           // 0..63
    const int tm = pb >> 3, cg = pb & 7; // rows tm*64.., cols cg*16..
    const int tid = threadIdx.x;
    const int lane = tid & 63, ws = tid >> 6;
    const int l15 = lane & 15, qd = lane >> 4;

    const u16* ap[4];
#pragma unroll
    for (int g = 0; g < 4; ++g)
        ap[g] = pH1 + (size_t)(tm * 4 + g) * (KH_H * 512) + lane * 8;
    const u16* bp = pWo + (size_t)cg * (KH_WO * 512) + lane * 8;

    f4 acc[4];
#pragma unroll
    for (int g = 0; g < 4; ++g) acc[g] = (f4)(0.f);

    for (int m = 0; m < 4; ++m) {
#pragma unroll
        for (int sh = 0; sh < 2; ++sh) {
            const int o = (((ws + m * 4) << 1) + sh) * 512;
            const bf8 Bv = ld8(bp + o);
#pragma unroll
            for (int g = 0; g < 4; ++g)
                acc[g] = MFMA16(ld8(ap[g] + o), Bv, acc[g]);
        }
    }

#pragma unroll
    for (int g = 0; g < 4; ++g)
#pragma unroll
        for (int r = 0; r < 4; ++r)
            red[ws * RSZ + (g * 16 + qd * 4 + r) * RSTRIDE + l15] = acc[g][r];
    __syncthreads();

    const int row = tid >> 2, c4 = (tid & 3) * 4;
    const int col = cg * 16 + c4;
    const int grow = tm * 64 + row;
    f4 s;
#pragma unroll
    for (int j = 0; j < 4; ++j) {
        const int cidx = row * RSTRIDE + c4 + j;
        s[j] = red[0 * RSZ + cidx] + red[1 * RSZ + cidx]
             + red[2 * RSZ + cidx] + red[3 * RSZ + cidx];
    }
    const f4 v = *(const f4*)&xin[(size_t)grow * ldxin + col] + s
                 + *(const f4*)&bout_[col];
    *(f4*)&XL[(size_t)grow * LDXL + col] = v;
    us4 b;
#pragma unroll
    for (int j = 0; j < 4; ++j) b[j] = f2bf(v[j]);
    *(us4*)&XLbf[swz(KH_XL, grow, col)] = b;
    *(f4*)&dout[(size_t)grow * OUTROW + slot * IN_ + col] = v;
}

// ---- Fused proj(g-1)-prologue + cell0(g), grid EXACTLY 512 (= capacity).
// Blocks 0..63: proj(g-1) first (reads H1(g-1)/XL — prior dispatches), write
// XLbf via sc0sc1 (-> LLC), vmcnt-drain, RELAXED flag-add (no fence -> no L2
// invalidation; weights stay L2-resident — the R6 failure mode avoided).
// All blocks: cell0(g) with h-tiles FIRST; waves 0,1 spin on flag (relaxed)
// then consume their single x-tile from XLbf via sc0sc1 loads. Per-wave
// K-column sets identical to cell_body (x moved last within waves 0,1 only).
__global__ __launch_bounds__(256, 2) void fuse0_k(
    const u16* __restrict__ pH1, const u16* __restrict__ pWo,
    const float* __restrict__ bout_,
    const float* __restrict__ xin, int ldxin,
    float* __restrict__ XL, u16* __restrict__ XLbf,
    float* __restrict__ dout, int slot,
    const u16* __restrict__ pH0, const u16* __restrict__ pW0,
    const float* __restrict__ bias, float* __restrict__ Cst,
    u16* __restrict__ Hdst, u32* flag, u32 target)
{
    __shared__ float red[4 * RSZ];
    const int bid = blockIdx.x;
    const int tid = threadIdx.x;
    const int lane = tid & 63, ws = tid >> 6;
    const int l15 = lane & 15, qd = lane >> 4, q4 = qd * 4;

    // cell coords; prefetch c RMW values now (prior-dispatch data)
    const int tn = (bid & 7) * 8 + ((bid >> 3) & 7);
    const int tm = bid >> 6;
    const int erow = ws * 16 + l15;
    const int grow = tm * 64 + erow;
    const int colb = tn * 16 + q4;
    const f4 cold = *(const f4*)&Cst[(size_t)grow * LDC + colb];

    if (bid < 64) {
        // ---- proj(g-1) prologue (proj64 body; XLbf via sc stores) ----
        const int ptm = bid >> 3, cg = bid & 7;
        const u16* ap[4];
#pragma unroll
        for (int g = 0; g < 4; ++g)
            ap[g] = pH1 + (size_t)(ptm * 4 + g) * (KH_H * 512) + lane * 8;
        const u16* pbp = pWo + (size_t)cg * (KH_WO * 512) + lane * 8;

        f4 pacc[4];
#pragma unroll
        for (int g = 0; g < 4; ++g) pacc[g] = (f4)(0.f);
        for (int m = 0; m < 4; ++m) {
#pragma unroll
            for (int sh = 0; sh < 2; ++sh) {
                const int o = (((ws + m * 4) << 1) + sh) * 512;
                const bf8 Bv = ld8(pbp + o);
#pragma unroll
                for (int g = 0; g < 4; ++g)
                    pacc[g] = MFMA16(ld8(ap[g] + o), Bv, pacc[g]);
            }
        }
#pragma unroll
        for (int g = 0; g < 4; ++g)
#pragma unroll
            for (int r = 0; r < 4; ++r)
                red[ws * RSZ + (g * 16 + qd * 4 + r) * RSTRIDE + l15] = pacc[g][r];
        __syncthreads();

        const int prow = tid >> 2, c4 = (tid & 3) * 4;
        const int col = cg * 16 + c4;
        const int pgrow = ptm * 64 + prow;
        f4 s;
#pragma unroll
        for (int j = 0; j < 4; ++j) {
            const int cidx = prow * RSTRIDE + c4 + j;
            s[j] = red[0 * RSZ + cidx] + red[1 * RSZ + cidx]
                 + red[2 * RSZ + cidx] + red[3 * RSZ + cidx];
        }
        const f4 v = *(const f4*)&xin[(size_t)pgrow * ldxin + col] + s
                     + *(const f4*)&bout_[col];
        *(f4*)&XL[(size_t)pgrow * LDXL + col] = v;
        *(f4*)&dout[(size_t)pgrow * OUTROW + slot * IN_ + col] = v;
        us4 b;
#pragma unroll
        for (int j = 0; j < 4; ++j) b[j] = f2bf(v[j]);
        st8_cc(&XLbf[swz(KH_XL, pgrow, col)], b);
        asm volatile("s_waitcnt vmcnt(0)" ::: "memory");   // sc stores at LLC
        __syncthreads();                                   // red free; all stores drained
        if (tid == 0)
            __hip_atomic_fetch_add(flag, 1u, __ATOMIC_RELAXED,
                                   __HIP_MEMORY_SCOPE_AGENT);
    }

    // ---- cell0(g): h-part GEMM (16 h-tiles; wave ws -> 4 tiles) ----
    f4 acc[4][4];
#pragma unroll
    for (int i = 0; i < 4; ++i)
#pragma unroll
        for (int j = 0; j < 4; ++j) acc[i][j] = (f4)(0.f);

    const u16* bp[4];
#pragma unroll
    for (int t = 0; t < 4; ++t)
        bp[t] = pW0 + (size_t)(tn * 4 + t) * (KH_W0 * 512) + lane * 8;
    const u16* ah[4];
#pragma unroll
    for (int g = 0; g < 4; ++g)
        ah[g] = pH0 + (size_t)(tm * 4 + g) * (KH_H * 512) + lane * 8;

    // wave ws h-tile indices: j = j0 + 4m (same K-set as cell_body's split)
    const int j0 = (ws < 2) ? ws + 2 : ws - 2;

#define LOADH(AS, BS, Q)                                                    \
  do {                                                                      \
    const int j_ = j0 + ((((Q) >> 1)) << 2);                                \
    const int oA_ = (2 * j_ + ((Q) & 1)) * 512;                             \
    _Pragma("unroll")                                                       \
    for (int g_ = 0; g_ < 4; ++g_) AS[g_] = ld8(ah[g_] + oA_);              \
    _Pragma("unroll")                                                       \
    for (int t_ = 0; t_ < 4; ++t_) BS[t_] = ld8(bp[t_] + oA_ + 4 * 512);    \
  } while (0)

    {
        bf8 A0[4], B0[4], A1[4], B1[4];
        LOADH(A0, B0, 0);
        for (int q = 0; q < 8; q += 2) {
            LOADH(A1, B1, q + 1);
            MFMAP(A0, B0);
            if (q + 2 < 8) LOADH(A0, B0, q + 2);
            MFMAP(A1, B1);
        }
    }
#undef LOADH

    // ---- x-part (waves 0,1 only): spin (relaxed, no fence) then sc loads ----
    if (ws < 2) {
        while (__hip_atomic_load(flag, __ATOMIC_RELAXED,
                                 __HIP_MEMORY_SCOPE_AGENT) < target)
            __builtin_amdgcn_s_sleep(4);
        const u16* xp[4];
#pragma unroll
        for (int g = 0; g < 4; ++g)
            xp[g] = XLbf + (size_t)(tm * 4 + g) * (KH_XL * 512) + lane * 8;
        bf8 XA[2][4], XB[2][4];
#pragma unroll
        for (int sh = 0; sh < 2; ++sh) {
            const int o = (2 * ws + sh) * 512;
#pragma unroll
            for (int g = 0; g < 4; ++g) XA[sh][g] = ld8_cc(xp[g] + o);
#pragma unroll
            for (int t = 0; t < 4; ++t) XB[sh][t] = ld8(bp[t] + o);  // W0c x kh
        }
        asm volatile("s_waitcnt vmcnt(0)"
                     : "+v"(XA[0][0]), "+v"(XA[0][1]), "+v"(XA[0][2]), "+v"(XA[0][3]),
                       "+v"(XA[1][0]), "+v"(XA[1][1]), "+v"(XA[1][2]), "+v"(XA[1][3]) ::);
        __builtin_amdgcn_sched_barrier(0);
#pragma unroll
        for (int sh = 0; sh < 2; ++sh) MFMAP(XA[sh], XB[sh]);
    }

    // ---- reduction + cell epilogue (identical to cell_body) ----
    __syncthreads();    // prologue blocks: ensure red reads done everywhere
#pragma unroll
    for (int rg = 0; rg < 4; ++rg)
#pragma unroll
        for (int t = 0; t < 4; ++t)
#pragma unroll
            for (int r = 0; r < 4; ++r)
                red[ws * RSZ + (rg * 16 + q4 + r) * RSTRIDE + t * 16 + l15] = acc[rg][t][r];
    __syncthreads();

    f4 gs[4];
#pragma unroll
    for (int G = 0; G < 4; ++G) {
        f4 s;
#pragma unroll
        for (int j = 0; j < 4; ++j) {
            const int cidx = erow * RSTRIDE + G * 16 + q4 + j;
            s[j] = red[0 * RSZ + cidx] + red[1 * RSZ + cidx]
                 + red[2 * RSZ + cidx] + red[3 * RSZ + cidx];
        }
        gs[G] = s + *(const f4*)&bias[tn * 64 + G * 16 + q4];
    }
    f4 cn; us4 h4;
#pragma unroll
    for (int j = 0; j < 4; ++j) {
        const float I  = sigm(gs[0][j]);
        const float F  = sigm(gs[1][j]);
        const float Gg = tanh_f(gs[2][j]);
        const float O  = sigm(gs[3][j]);
        cn[j] = F * cold[j] + I * Gg;
        h4[j] = f2bf(O * tanh_f(cn[j]));
    }
    *(f4*)&Cst[(size_t)grow * LDC + colb] = cn;
    *(us4*)&Hdst[swz(KH_H, grow, colb)] = h4;
}

// ---- Weight conversion: fp32 -> bf16 fragment-linear, gate-permuted rows,
// fused biases. One block per fragment; thread t writes u32 pair (coalesced).
__global__ void conv_w(const float* Wih0, const float* Whh0, const float* bih0, const float* bhh0,
                       const float* Wih1, const float* Whh1, const float* bih1, const float* bhh1,
                       const float* Wout,
                       u16* W0c, float* b0p, u16* W1c, float* b1p, u16* Woutb)
{
    const int bid = blockIdx.x, t = threadIdx.x;
    const int lane = t >> 2;              // fragment lane 0..63
    const int l15 = lane & 15, qd = lane >> 4;
    const int j0 = (t & 3) * 2;
    const int c0_ = qd * 8 + j0;

    if (bid < 9216) {                     // W0c: 256 rowgrps x 36 kh
        const int rg = bid / 36, kh = bid - rg * 36;
        const int p = rg * 16 + l15;
        const int rem = p & 63, G = rem >> 4, u = (p >> 6) * 16 + (rem & 15);
        const int src = G * H_ + u;
        float e0, e1;
        if (kh < 4) {
            e0 = Wih0[(size_t)src * IN_ + kh * 32 + c0_];
            e1 = Wih0[(size_t)src * IN_ + kh * 32 + c0_ + 1];
        } else {
            e0 = Whh0[(size_t)src * H_ + (kh - 4) * 32 + c0_];
            e1 = Whh0[(size_t)src * H_ + (kh - 4) * 32 + c0_ + 1];
        }
        ((u32*)W0c)[(size_t)bid * 256 + t] = (u32)f2bf(e0) | ((u32)f2bf(e1) << 16);
        if (kh == 0 && qd == 0 && j0 == 0) b0p[p] = bih0[src] + bhh0[src];
    } else if (bid < 25600) {             // W1c: 256 rowgrps x 64 kh
        const int x = bid - 9216;
        const int rg = x >> 6, kh = x & 63;
        const int p = rg * 16 + l15;
        const int rem = p & 63, G = rem >> 4, u = (p >> 6) * 16 + (rem & 15);
        const int src = G * H_ + u;
        float e0, e1;
        if (kh < 32) {
            e0 = Wih1[(size_t)src * H_ + kh * 32 + c0_];
            e1 = Wih1[(size_t)src * H_ + kh * 32 + c0_ + 1];
        } else {
            e0 = Whh1[(size_t)src * H_ + (kh - 32) * 32 + c0_];
            e1 = Whh1[(size_t)src * H_ + (kh - 32) * 32 + c0_ + 1];
        }
        ((u32*)W1c)[(size_t)x * 256 + t] = (u32)f2bf(e0) | ((u32)f2bf(e1) << 16);
        if (kh == 0 && qd == 0 && j0 == 0) b1p[p] = bih1[src] + bhh1[src];
    } else {                              // Woutb: 8 rowgrps x 32 kh
        const int x = bid - 25600;
        const int rg = x >> 5, kh = x & 31;
        const int r = rg * 16 + l15;
        const float e0 = Wout[(size_t)r * H_ + kh * 32 + c0_];
        const float e1 = Wout[(size_t)r * H_ + kh * 32 + c0_ + 1];
        ((u32*)Woutb)[(size_t)x * 256 + t] = (u32)f2bf(e0) | ((u32)f2bf(e1) << 16);
    }
}

// ---- Setup: zero states + handoff flag, x -> bf16 staging, x -> out[:,0:16] ----
__global__ void setup_k(const float* __restrict__ x, u16* __restrict__ Xb,
                        u16* H0, u16* H1, float* c0, float* c1,
                        float* __restrict__ dout, u32* flag)
{
    const int i = blockIdx.x * 256 + threadIdx.x;  // < 512*16*128
    if (i < 64) flag[i] = 0;                        // replay-safe epoch reset
    const float v = x[i];
    const int r = i >> 11, col = i & 2047;
    Xb[swz(KH_X, r, col)] = f2bf(v);
    dout[(size_t)r * OUTROW + col] = v;
    if (i < B_ * H_) {
        H0[i] = 0; H1[i] = 0;
        const int rr = i >> 10, cc = i & 1023;
        c0[(size_t)rr * LDC + cc] = 0.f; c1[(size_t)rr * LDC + cc] = 0.f;
    }
}

extern "C" void kernel_launch(void* const* d_in, const int* in_sizes, int n_in,
                              void* d_out, int out_size, void* d_ws, size_t ws_size,
                              hipStream_t stream)
{
    const float* x    = (const float*)d_in[0];
    const float* Wih0 = (const float*)d_in[1];
    const float* Whh0 = (const float*)d_in[2];
    const float* bih0 = (const float*)d_in[3];
    const float* bhh0 = (const float*)d_in[4];
    const float* Wih1 = (const float*)d_in[5];
    const float* Whh1 = (const float*)d_in[6];
    const float* bih1 = (const float*)d_in[7];
    const float* bhh1 = (const float*)d_in[8];
    const float* Wout = (const float*)d_in[9];
    const float* bout = (const float*)d_in[10];
    float* dout = (float*)d_out;

    char* ws = (char*)d_ws;
    size_t off = 0;
    auto alloc = [&](size_t bytes) -> char* {
        char* p = ws + off; off += (bytes + 255) & ~(size_t)255; return p;
    };
    u16*  W0c   = (u16*)alloc((size_t)9216 * 1024);
    u16*  W1c   = (u16*)alloc((size_t)16384 * 1024);
    u16*  Woutb = (u16*)alloc((size_t)256 * 1024);
    float* b0p  = (float*)alloc(4096 * 4);
    float* b1p  = (float*)alloc(4096 * 4);
    u16*  Xb    = (u16*)alloc((size_t)2048 * 1024);
    u16*  H0b[2]; H0b[0] = (u16*)alloc((size_t)1024 * 1024); H0b[1] = (u16*)alloc((size_t)1024 * 1024);
    u16*  H1b[2]; H1b[0] = (u16*)alloc((size_t)1024 * 1024); H1b[1] = (u16*)alloc((size_t)1024 * 1024);
    float* c0   = (float*)alloc((size_t)B_ * LDC * 4);
    float* c1   = (float*)alloc((size_t)B_ * LDC * 4);
    float* XL   = (float*)alloc((size_t)B_ * LDXL * 4);
    u16*  XLbf  = (u16*)alloc((size_t)128 * 1024);
    u32*  flag  = (u32*)alloc(256 * 4);

    conv_w<<<25856, 256, 0, stream>>>(Wih0, Whh0, bih0, bhh0,
                                      Wih1, Whh1, bih1, bhh1, Wout,
                                      W0c, b0p, W1c, b1p, Woutb);
    setup_k<<<4096, 256, 0, stream>>>(x, Xb, H0b[0], H1b[0], c0, c1, dout, flag);

    // ---- prompt: cell0(0); 15 x [cell1(t) || cell0(t+1)]; cell1(15)
    int p = 0;
    cell_gemm<<<512, 256, 0, stream>>>(Xb, KH_X, 2, H0b[0], KH_H, 16,
                                       W0c, KH_W0, b0p, c0, H0b[1]);
    for (int g = 0; g < 15; ++g) {
        pair_k<<<1024, 256, 0, stream>>>(
            H0b[1 - p], KH_H, 16, H1b[p], KH_H, 16, W1c, KH_W1, b1p, c1, H1b[1 - p],
            Xb + (size_t)(g + 1) * 2048, KH_X, 2, H0b[1 - p], KH_H, 16,
            W0c, KH_W0, b0p, c0, H0b[p]);
        p ^= 1;
    }
    // here p = 1: cell0(15) wrote H0b[0]; latest H1 = H1b[1]
    cell_gemm<<<512, 256, 0, stream>>>(H0b[0], KH_H, 16, H1b[1], KH_H, 16,
                                       W1c, KH_W1, b1p, c1, H1b[0]);   // h1(15)

    // ---- rollout: 63 x [fused proj(g-1)+cell0(g); cell1(g)] + final proj(78)
    // fuse e: prologue proj emits dout slot 16+e (e=0 -> proj(15), xin = x[:,15])
    p = 0;
    for (int e = 0; e < 63; ++e) {
        const float* xin; int ldxin;
        if (e == 0) { xin = x + 15 * IN_; ldxin = L_ * IN_; }
        else        { xin = XL;           ldxin = LDXL;     }
        fuse0_k<<<512, 256, 0, stream>>>(H1b[p], Woutb, bout, xin, ldxin,
                                         XL, XLbf, dout, 16 + e,
                                         H0b[p], W0c, b0p, c0, H0b[1 - p],
                                         flag, 64u * (u32)(e + 1));
        cell_gemm<<<512, 256, 0, stream>>>(H0b[1 - p], KH_H, 16, H1b[p], KH_H, 16,
                                           W1c, KH_W1, b1p, c1, H1b[1 - p]);
        p ^= 1;
    }
    // p = 1: latest H1 = H1b[1]; final projection -> slot 79
    proj64_k<<<64, 256, 0, stream>>>(H1b[1], Woutb, bout,
                                     XL, LDXL, XL, XLbf, dout, 79);
}